// Round 1
// baseline (893.872 us; speedup 1.0000x reference)
//
#include <hip/hip_runtime.h>

// TensorProduct (e3nn uvu, no weights): out[n, mu3[k], c] += cg[k] * x[n, mu1[k], c] * y[n, mu2[k], c]
// x,y: [4096, 16, 128] fp32 ; out: [4096, 99, 128] fp32 ; nnz ~ 350.
//
// Strategy: scatter runtime (mu1,mu2,mu3,cg) into dense W[16][16][99] in d_ws,
// then a fully-unrolled main kernel walks a compile-time SUPERSET of the real
// Wigner-3j sparsity (selection rules: |m3| in {|m1|+|m2|, ||m1|-|m2||} and an
// even count of negative m's — both provably necessary for l1+l2+l3 even,
// which covers all 23 paths here). Superset entries that are actually zero
// read W=0 and add nothing. This keeps x (16), y (16), acc (99) all in
// registers with static indices — ~615 VALU ops per (edge,channel) thread —
// so the kernel is purely HBM-bound (262 MB traffic -> ~42 us floor).

#define LMAX     3
#define DIM_IN   16
#define DIM_OUT  99
#define CHANNELS 128
#define N_EDGES  4096

// Output offset of path (L1,L2,L3), mirroring the reference's enumeration
// order exactly. Input irrep offset is simply l*l (cumsum of 2l+1).
__host__ __device__ constexpr int out_offset(int L1, int L2, int L3) {
    int off = 0;
    for (int l1 = 0; l1 <= LMAX; ++l1) {
        for (int l2 = 0; l2 <= LMAX; ++l2) {
            int lo = l1 > l2 ? l1 - l2 : l2 - l1;
            for (int l3 = lo; l3 <= l1 + l2; ++l3) {
                if (l3 <= LMAX && (((l1 + l2 + l3) & 1) == 0)) {
                    if (l1 == L1 && l2 == L2 && l3 == L3) return off;
                    off += 2 * l3 + 1;
                }
            }
        }
    }
    return 0; // unreachable for valid paths
}

// ---------------- prep: scatter sparse metadata into dense W ----------------
__global__ void build_w_kernel(const int* __restrict__ mu1,
                               const int* __restrict__ mu2,
                               const int* __restrict__ mu3,
                               const float* __restrict__ cg,
                               float* __restrict__ W, int nnz) {
    int k = blockIdx.x * blockDim.x + threadIdx.x;
    if (k < nnz) {
        W[(mu1[k] * DIM_IN + mu2[k]) * DIM_OUT + mu3[k]] = cg[k];
    }
}

// ---------------- main: one thread per (edge, channel) ----------------
__global__ __launch_bounds__(256) void tp_kernel(
        const float* __restrict__ x, const float* __restrict__ y,
        const float* __restrict__ W, float* __restrict__ out) {
    const int t = blockIdx.x * blockDim.x + threadIdx.x;
    const int c = t & (CHANNELS - 1);
    const int n = t >> 7; // CHANNELS == 128

    const float* xp = x + (size_t)n * DIM_IN * CHANNELS + c;
    const float* yp = y + (size_t)n * DIM_IN * CHANNELS + c;

    float xv[DIM_IN], yv[DIM_IN];
#pragma unroll
    for (int i = 0; i < DIM_IN; ++i) {
        xv[i] = xp[i * CHANNELS];
        yv[i] = yp[i * CHANNELS];
    }

    float acc[DIM_OUT];
#pragma unroll
    for (int j = 0; j < DIM_OUT; ++j) acc[j] = 0.0f;

    // Fully-unrolled compile-time superset walk. All l/m loop vars fold to
    // constants, so xv/yv/acc indices are static -> registers.
#pragma unroll
    for (int l1 = 0; l1 <= LMAX; ++l1) {
#pragma unroll
        for (int l2 = 0; l2 <= LMAX; ++l2) {
#pragma unroll
            for (int l3 = 0; l3 <= LMAX; ++l3) {
                const int lo = l1 > l2 ? l1 - l2 : l2 - l1;
                if (l3 >= lo && l3 <= l1 + l2 && (((l1 + l2 + l3) & 1) == 0)) {
                    const int o1 = l1 * l1;
                    const int o2 = l2 * l2;
                    const int o3 = out_offset(l1, l2, l3);
#pragma unroll
                    for (int m1 = -l1; m1 <= l1; ++m1) {
#pragma unroll
                        for (int m2 = -l2; m2 <= l2; ++m2) {
#pragma unroll
                            for (int m3 = -l3; m3 <= l3; ++m3) {
                                const int a1 = m1 < 0 ? -m1 : m1;
                                const int a2 = m2 < 0 ? -m2 : m2;
                                const int a3 = m3 < 0 ? -m3 : m3;
                                const int adiff = a1 > a2 ? a1 - a2 : a2 - a1;
                                const bool mag_ok = (a3 == a1 + a2) || (a3 == adiff);
                                const int negs = (m1 < 0) + (m2 < 0) + (m3 < 0);
                                if (mag_ok && ((negs & 1) == 0)) {
                                    const int i1 = o1 + l1 + m1;
                                    const int i2 = o2 + l2 + m2;
                                    const int i3 = o3 + l3 + m3;
                                    const float w = W[(i1 * DIM_IN + i2) * DIM_OUT + i3];
                                    acc[i3] += w * xv[i1] * yv[i2];
                                }
                            }
                        }
                    }
                }
            }
        }
    }

    float* op = out + (size_t)n * DIM_OUT * CHANNELS + c;
#pragma unroll
    for (int j = 0; j < DIM_OUT; ++j) op[j * CHANNELS] = acc[j];
}

extern "C" void kernel_launch(void* const* d_in, const int* in_sizes, int n_in,
                              void* d_out, int out_size, void* d_ws, size_t ws_size,
                              hipStream_t stream) {
    const float* x   = (const float*)d_in[0];
    const float* y   = (const float*)d_in[1];
    const int*   mu1 = (const int*)d_in[2];
    const int*   mu2 = (const int*)d_in[3];
    const int*   mu3 = (const int*)d_in[4];
    const float* cg  = (const float*)d_in[5];
    const int nnz = in_sizes[2];

    float* W = (float*)d_ws; // 16*16*99*4 = 101376 bytes

    // d_ws is re-poisoned before every timed launch -> must zero every call.
    hipMemsetAsync(W, 0, DIM_IN * DIM_IN * DIM_OUT * sizeof(float), stream);
    build_w_kernel<<<(nnz + 255) / 256, 256, 0, stream>>>(mu1, mu2, mu3, cg, W, nnz);

    const int total = N_EDGES * CHANNELS;
    tp_kernel<<<total / 256, 256, 0, stream>>>(x, y, W, (float*)d_out);
}

// Round 2
// 271.389 us; speedup vs baseline: 3.2937x; 3.2937x over previous
//
#include <hip/hip_runtime.h>
#include <utility>

// TensorProduct (e3nn uvu, no weights): out[n, mu3[k], c] += cg[k] * x[n, mu1[k], c] * y[n, mu2[k], c]
// x,y: [4096, 16, 128] fp32 ; out: [4096, 99, 128] fp32 ; nnz ~ 350.
//
// R1 lesson: #pragma-unroll nest didn't fully unroll -> acc[99]/xv/yv demoted
// to scratch (VGPR=40, +615 MB scratch traffic, 706 us). This version forces
// full unrolling via integer_sequence fold-expressions (every index is a
// compile-time constant by construction) AND restructures output-outermost so
// the accumulator is a single scalar per output element (spill-proof).
//
// Sparsity superset (provably necessary selection rules for real-basis Wigner
// 3j with l1+l2+l3 even): |m3| in {|m1|+|m2|, ||m1|-|m2||} and an even number
// of negative m's. Runtime (mu1,mu2,mu3,cg) is scattered into dense
// W[16][16][99]; superset entries that are actually zero contribute 0.

#define LMAX     3
#define DIM_IN   16
#define DIM_OUT  99
#define CHANNELS 128
#define N_EDGES  4096

struct Path { int l1, l2, l3, o3; };
constexpr int NPATHS = 23;

struct PathList { Path p[NPATHS]; };

constexpr PathList make_paths() {
    PathList r{};
    int idx = 0, off = 0;
    for (int l1 = 0; l1 <= LMAX; ++l1)
        for (int l2 = 0; l2 <= LMAX; ++l2) {
            int lo = l1 > l2 ? l1 - l2 : l2 - l1;
            for (int l3 = lo; l3 <= l1 + l2; ++l3)
                if (l3 <= LMAX && (((l1 + l2 + l3) & 1) == 0)) {
                    r.p[idx].l1 = l1; r.p[idx].l2 = l2;
                    r.p[idx].l3 = l3; r.p[idx].o3 = off;
                    ++idx; off += 2 * l3 + 1;
                }
        }
    return r;
}
constexpr PathList PATHS = make_paths();  // off ends at 99

// ---- compile-time for: f(integral_constant<int,0>) ... f(<N-1>) ----
template <int... Is, typename F>
__device__ __forceinline__ void static_for_impl(std::integer_sequence<int, Is...>, F&& f) {
    (f(std::integral_constant<int, Is>{}), ...);
}
template <int N, typename F>
__device__ __forceinline__ void static_for(F&& f) {
    static_for_impl(std::make_integer_sequence<int, N>{}, static_cast<F&&>(f));
}

// ---------------- prep: scatter sparse metadata into dense W ----------------
__global__ void build_w_kernel(const int* __restrict__ mu1,
                               const int* __restrict__ mu2,
                               const int* __restrict__ mu3,
                               const float* __restrict__ cg,
                               float* __restrict__ W, int nnz) {
    int k = blockIdx.x * blockDim.x + threadIdx.x;
    if (k < nnz) {
        W[(mu1[k] * DIM_IN + mu2[k]) * DIM_OUT + mu3[k]] = cg[k];
    }
}

// ---------------- main: one thread per (edge, channel) ----------------
__global__ __launch_bounds__(256) void tp_kernel(
        const float* __restrict__ x, const float* __restrict__ y,
        const float* __restrict__ W, float* __restrict__ out) {
    const int t = blockIdx.x * blockDim.x + threadIdx.x;
    const int c = t & (CHANNELS - 1);
    const int n = t >> 7; // CHANNELS == 128

    const float* xp = x + (size_t)n * DIM_IN * CHANNELS + c;
    const float* yp = y + (size_t)n * DIM_IN * CHANNELS + c;

    float xv[DIM_IN], yv[DIM_IN];
    static_for<DIM_IN>([&](auto I) {
        constexpr int i = decltype(I)::value;
        xv[i] = xp[i * CHANNELS];
        yv[i] = yp[i * CHANNELS];
    });

    float* op = out + (size_t)n * DIM_OUT * CHANNELS + c;

    static_for<NPATHS>([&](auto P) {
        constexpr int p  = decltype(P)::value;
        constexpr int l1 = PATHS.p[p].l1;
        constexpr int l2 = PATHS.p[p].l2;
        constexpr int l3 = PATHS.p[p].l3;
        constexpr int o3 = PATHS.p[p].o3;

        static_for<2 * l3 + 1>([&](auto M3) {
            constexpr int m3 = decltype(M3)::value - l3;
            float s = 0.0f;

            static_for<2 * l1 + 1>([&](auto M1) {
                constexpr int m1 = decltype(M1)::value - l1;
                static_for<2 * l2 + 1>([&](auto M2) {
                    constexpr int m2 = decltype(M2)::value - l2;
                    constexpr int a1 = m1 < 0 ? -m1 : m1;
                    constexpr int a2 = m2 < 0 ? -m2 : m2;
                    constexpr int a3 = m3 < 0 ? -m3 : m3;
                    constexpr int adiff = a1 > a2 ? a1 - a2 : a2 - a1;
                    constexpr bool mag_ok = (a3 == a1 + a2) || (a3 == adiff);
                    constexpr int negs = (m1 < 0) + (m2 < 0) + (m3 < 0);
                    if constexpr (mag_ok && ((negs & 1) == 0)) {
                        constexpr int i1 = l1 * l1 + l1 + m1;
                        constexpr int i2 = l2 * l2 + l2 + m2;
                        constexpr int i3 = o3 + l3 + m3;
                        s += W[(i1 * DIM_IN + i2) * DIM_OUT + i3] * xv[i1] * yv[i2];
                    }
                });
            });

            constexpr int i3 = o3 + l3 + m3;
            op[i3 * CHANNELS] = s;
        });
    });
}

extern "C" void kernel_launch(void* const* d_in, const int* in_sizes, int n_in,
                              void* d_out, int out_size, void* d_ws, size_t ws_size,
                              hipStream_t stream) {
    const float* x   = (const float*)d_in[0];
    const float* y   = (const float*)d_in[1];
    const int*   mu1 = (const int*)d_in[2];
    const int*   mu2 = (const int*)d_in[3];
    const int*   mu3 = (const int*)d_in[4];
    const float* cg  = (const float*)d_in[5];
    const int nnz = in_sizes[2];

    float* W = (float*)d_ws; // 16*16*99*4 = 101376 bytes

    // d_ws is re-poisoned before every timed launch -> must zero every call.
    hipMemsetAsync(W, 0, DIM_IN * DIM_IN * DIM_OUT * sizeof(float), stream);
    build_w_kernel<<<(nnz + 255) / 256, 256, 0, stream>>>(mu1, mu2, mu3, cg, W, nnz);

    const int total = N_EDGES * CHANNELS;
    tp_kernel<<<total / 256, 256, 0, stream>>>(x, y, W, (float*)d_out);
}